// Round 5
// baseline (292.500 us; speedup 1.0000x reference)
//
#include <hip/hip_runtime.h>
#include <stdint.h>

typedef unsigned long long u64;
typedef unsigned int u32;

#define NA 10647            // total anchors: (52*52 + 26*26 + 13*13) * 3
#define NCLS 20
#define CAP 2048            // per-class capacity (mean 532, huge headroom)
#define OUT_SCORES 42588    // NA*4
#define OUT_CLS    53235    // NA*5
#define OUT_KEEP   63882    // NA*6

// anchors[level][a] * scale{4,2,1}
__constant__ float c_aw[9] = {4.f,8.f,12.f, 3.f,6.f,8.f, 3.5f,5.f,8.f};
__constant__ float c_ah[9] = {6.f,12.f,10.f, 7.f,8.f,6.f, 5.f,4.5f,8.f};

__device__ __forceinline__ float sig(float x){ return 1.0f/(1.0f+expf(-x)); }

// ---------------- Phase 1: decode, a-major (coalesced) + class-bucket scatter
__global__ void decode_kernel(const float* __restrict__ p1, const float* __restrict__ p2,
                              const float* __restrict__ p3, float* __restrict__ out,
                              float4* __restrict__ box4, u64* __restrict__ bucket,
                              int* __restrict__ cls_cnt, float* __restrict__ keep_out)
{
    int t = blockIdx.x*256 + threadIdx.x;
    if (t >= NA) return;
    const float* p; int base, HW, L; float s;
    int a, hw, h, w;
    if (t < 8112){
        p=p1; base=0; HW=2704; s=8.f; L=0;
        a = t/2704; hw = t - a*2704; h = hw/52; w = hw - h*52;
    } else if (t < 10140){
        int r = t - 8112;
        p=p2; base=8112; HW=676; s=16.f; L=1;
        a = r/676; hw = r - a*676; h = hw/26; w = hw - h*26;
    } else {
        int r = t - 10140;
        p=p3; base=10140; HW=169; s=32.f; L=2;
        a = r/169; hw = r - a*169; h = hw/13; w = hw - h*13;
    }
    int n = base + hw*3 + a;   // original anchor index (reference layout)

    // layout: pred[0, ch, h, w] = p[ch*HW + hw];  obj=ch a, cls=ch 3+a*20+c, xywh=ch 63+a*4+j
    float obj = sig(p[(size_t)a*HW + hw]);

    float e[NCLS];
    #pragma unroll
    for (int c=0;c<NCLS;c++) e[c] = p[(size_t)(3 + a*NCLS + c)*HW + hw];
    float xmax = e[0];
    #pragma unroll
    for (int c=1;c<NCLS;c++) xmax = fmaxf(xmax, e[c]);
    float ssum = 0.f;
    #pragma unroll
    for (int c=0;c<NCLS;c++){ e[c] = expf(e[c]-xmax); ssum += e[c]; }
    // mirror ref: all_class = (exp/sum)*obj, argmax first-max, score = max
    float best = -1.0f; int bi = 0;
    #pragma unroll
    for (int c=0;c<NCLS;c++){ float v = (e[c]/ssum)*obj; if (v > best){ best=v; bi=c; } }

    int xb = 63 + a*4;
    float tx = p[(size_t)(xb+0)*HW + hw];
    float ty = p[(size_t)(xb+1)*HW + hw];
    float tw = p[(size_t)(xb+2)*HW + hw];
    float th = p[(size_t)(xb+3)*HW + hw];
    float aw = c_aw[L*3+a], ah = c_ah[L*3+a];
    if (hw == HW-1){ aw=0.f; ah=0.f; }          // ref quirk: awh[hs*ws-1]=0 per level
    float cx = sig(tx) + (float)w;
    float cy = sig(ty) + (float)h;
    float bw = expf(tw)*aw, bh = expf(th)*ah;
    float hx = bw*0.5f,  hy = bh*0.5f;
    float x1 = ((cx-hx)*s)/416.0f;
    float y1 = ((cy-hy)*s)/416.0f;
    float x2 = ((cx+hx)*s)/416.0f;
    float y2 = ((cy+hy)*s)/416.0f;

    out[n*4+0] = fminf(fmaxf(x1*416.0f,0.f),415.f)/416.0f;
    out[n*4+1] = fminf(fmaxf(y1*416.0f,0.f),415.f)/416.0f;
    out[n*4+2] = fminf(fmaxf(x2*416.0f,0.f),415.f)/416.0f;
    out[n*4+3] = fminf(fmaxf(y2*416.0f,0.f),415.f)/416.0f;
    out[OUT_SCORES + n] = best;
    out[OUT_CLS    + n] = (float)bi;

    box4[n] = make_float4(x1,y1,x2,y2);

    // stable argsort(-scores): ascending key (~score_bits, idx); scores > 0 so bits monotone.
    u64 key = ((u64)(~__float_as_uint(best)) << 32) | (u32)n;
    int pos = atomicAdd(&cls_cnt[bi], 1);
    if (pos < CAP) bucket[(size_t)bi*CAP + pos] = key;
    else keep_out[n] = 0.0f;   // statistically unreachable; avoid poison leak
}

// ---------------- Phase 2: fused per-class sort + NMS (20 blocks x 512) ------
// Bucket -> LDS bitonic sort by (~score,idx) -> chunked greedy NMS.
// Row boxes live in per-lane REGISTERS; the 64-row inner loops broadcast them
// with __shfl(v, const_lane) -> v_readlane: pure VALU, no LDS-pipe pressure.
__global__ __launch_bounds__(512) void nms_all(
    const float4* __restrict__ box4, const u64* __restrict__ bucket,
    const int* __restrict__ cls_cnt, float* __restrict__ keep_out)
{
    int b = blockIdx.x;
    int tid = threadIdx.x, wv = tid>>6, ln = tid&63;
    __shared__ u64    lkey[CAP];          // 16 KB
    __shared__ float4 lbox[CAP];          // 32 KB
    __shared__ u64 validw[CAP/64];
    __shared__ u64 remw[CAP/64];
    __shared__ u64 keepw_s[CAP/64];
    __shared__ u64 keep_bc;

    int M = cls_cnt[b];
    if (M > CAP) M = CAP;
    const u64* gK = bucket + (size_t)b*CAP;

    // ---- load bucket, pad to pow2, bitonic sort ----
    int P = 64; while (P < M) P <<= 1;
    for (int t = tid; t < P; t += 512) lkey[t] = (t < M) ? gK[t] : ~0ull;
    __syncthreads();
    for (int k = 2; k <= P; k <<= 1){
        for (int j = k >> 1; j > 0; j >>= 1){
            for (int t = tid; t < (P>>1); t += 512){
                int low = t & (j-1); int i1 = ((t ^ low) << 1) | low; int i2 = i1 | j;
                bool asc = (i1 & k) == 0;
                u64 A = lkey[i1], B = lkey[i2];
                if ((A > B) == asc){ lkey[i1] = B; lkey[i2] = A; }
            }
            __syncthreads();
        }
    }

    // ---- gather boxes into sorted LDS slots; valid = score >= 0.001 ----
    int MC = (M + 63) & ~63;
    int nw = MC >> 6;
    for (int t = tid; t < MC; t += 512){           // MC mult of 64 -> wave-granular
        float4 bx = make_float4(0.f,0.f,0.f,0.f);
        bool v = false;
        if (t < M){
            u64 key = lkey[t];
            bx = box4[(u32)key];
            float sc = __uint_as_float(~(u32)(key >> 32));
            v = (sc >= 0.001f);
        }
        lbox[t] = bx;
        u64 bm = __ballot(v);                       // (t&63)==ln, word-aligned per wave
        if (ln == 0) validw[t>>6] = bm;
    }
    for (int w = tid; w < nw; w += 512) remw[w] = 0ull;
    __syncthreads();

    // ---- chunked greedy NMS ----
    for (int c = 0; c < nw; c++){
        // per-wave row register cache: lane ln holds row c*64+ln
        float4 rb = lbox[c*64 + ln];
        float  ra = (rb.z - rb.x) * (rb.w - rb.y);

        // 1) serial greedy resolve of this chunk (wave 0): diag via readlane
        if (wv == 0){
            u64 colw = 0;                 // bit i: row i suppresses my column (lane)
            #pragma unroll
            for (int i = 0; i < 64; i++){
                float rx1=__shfl(rb.x,i), ry1=__shfl(rb.y,i);
                float rx2=__shfl(rb.z,i), ry2=__shfl(rb.w,i);
                float rra=__shfl(ra,i);
                float xx1=fmaxf(rx1,rb.x), yy1=fmaxf(ry1,rb.y);
                float xx2=fminf(rx2,rb.z), yy2=fminf(ry2,rb.w);
                float inter=fmaxf(1e-28f,xx2-xx1)*fmaxf(1e-28f,yy2-yy1);
                float iou = inter/((rra+ra)-inter);
                colw |= (u64)(iou > 0.5f) << i;
            }
            u64 rem  = remw[c];
            u64 cand = validw[c] & ~rem;
            u64 keepw = 0;
            while (cand){                          // uniform (cand same in all lanes)
                int bp = __builtin_ctzll(cand);
                u64 rowm = __ballot((colw >> bp) & 1ull);   // row bp's in-chunk word
                keepw |= 1ull << bp;
                cand &= ~(rowm | (1ull << bp));
            }
            if (ln == 0){ keepw_s[c] = keepw; keep_bc = keepw; }
        }
        __syncthreads();
        // scalarize the keep mask (guarantees s_cbranch skips per row)
        u64 kk_v = keep_bc;
        u32 klo = __builtin_amdgcn_readfirstlane((u32)kk_v);
        u32 khi = __builtin_amdgcn_readfirstlane((u32)(kk_v >> 32));

        // 2) forward suppression: thread owns column j; rows via readlane
        if ((klo | khi) && (c+1)*64 < MC){
            for (int j = (c+1)*64 + tid; j < MC; j += 512){
                float4 cb = lbox[j];
                float  ca = (cb.z - cb.x) * (cb.w - cb.y);
                bool s = false;
                #pragma unroll
                for (int i = 0; i < 64; i++){
                    bool on = (i < 32) ? ((klo >> i) & 1u) : ((khi >> (i-32)) & 1u);
                    if (on){                        // scalar branch, uniform
                        float rx1=__shfl(rb.x,i), ry1=__shfl(rb.y,i);
                        float rx2=__shfl(rb.z,i), ry2=__shfl(rb.w,i);
                        float rra=__shfl(ra,i);
                        float xx1=fmaxf(rx1,cb.x), yy1=fmaxf(ry1,cb.y);
                        float xx2=fminf(rx2,cb.z), yy2=fminf(ry2,cb.w);
                        float inter=fmaxf(1e-28f,xx2-xx1)*fmaxf(1e-28f,yy2-yy1);
                        float iou = inter/((rra+ca)-inter);
                        s |= (iou > 0.5f);
                    }
                }
                u64 bm = __ballot(s);               // j word-aligned per wave
                if (ln == 0 && bm) atomicOr(&remw[j>>6], bm);
            }
        }
        __syncthreads();
    }

    // ---- write keep bits back to original indices ----
    for (int t = tid; t < M; t += 512){
        keep_out[(u32)lkey[t]] = ((keepw_s[t>>6] >> (t&63)) & 1ull) ? 1.0f : 0.0f;
    }
}

// ---------------- launch -----------------------------------------------------
extern "C" void kernel_launch(void* const* d_in, const int* in_sizes, int n_in,
                              void* d_out, int out_size, void* d_ws, size_t ws_size,
                              hipStream_t stream) {
    const float* p1 = (const float*)d_in[0];
    const float* p2 = (const float*)d_in[1];
    const float* p3 = (const float*)d_in[2];
    float* out = (float*)d_out;

    char* ws = (char*)d_ws;
    size_t off = 0;
    auto alloc = [&](size_t bytes)->void*{ void* p = ws + off; off += (bytes + 255) & ~(size_t)255; return p; };
    float4* box4   = (float4*)alloc((size_t)NA*16);
    u64*    bucket = (u64*)   alloc((size_t)NCLS*CAP*8);
    int*    cls_cnt= (int*)   alloc((size_t)NCLS*4);

    hipMemsetAsync(cls_cnt, 0, NCLS*sizeof(int), stream);
    decode_kernel<<<(NA+255)/256, 256, 0, stream>>>(p1,p2,p3,out,box4,bucket,cls_cnt,
                                                    out + OUT_KEEP);
    nms_all     <<<NCLS, 512, 0, stream>>>(box4, bucket, cls_cnt, out + OUT_KEEP);
}